// Round 2
// baseline (11060.773 us; speedup 1.0000x reference)
//
#include <hip/hip_runtime.h>
#include <hip/hip_fp16.h>

// Problem dims
#define BB 128
#define LL 1024
#define EE 512
#define HH 1024
#define VV 256
// Scan decomposition: 8 clusters (one per XCD) x 16 blocks
#define NCLUST 8
#define JJ 16      // blocks per cluster (barrier participants)
#define BRR 16     // batch rows per cluster
#define HCC 64     // h-columns per block
#define PSTR 68    // padded row stride (words) for part[] to kill 4-way bank conflicts
#define LOSCL 2048.0f
#define ILOSCL (1.0f/2048.0f)

typedef __attribute__((ext_vector_type(8))) _Float16 f16x8;
typedef __attribute__((ext_vector_type(4))) float f32x4;
typedef unsigned long long u64;

union U16x8 { ulonglong2 u2; f16x8 f; _Float16 h[8]; u64 w[2]; };

// ws layout (bytes)
#define CNT_OFF 0                                   // 8 counters, 128B stride
#define EW_OFF  4096                                // embedW f32 [256][1024]       = 1 MB
#define S_OFF   (EW_OFF + VV*HH*4)                  // S f16 [2 par][2 plane][128][1024] = 1 MB
#define WHI_OFF (S_OFF + 2*2*BB*HH*2)               // W_h frag image 16 x 128KB    = 2 MB
#define WOI_OFF (WHI_OFF + JJ*4*32*64*16)           // W_out frag image             = 512 KB

// ---------------- prep kernels ----------------

// embedW[v][h] = sum_e embedding[v][e] * W_e[e][h] + b_h[h]   (f32, exact)
__global__ void k_embedw(const float* __restrict__ emb, const float* __restrict__ We,
                         const float* __restrict__ bh, float* __restrict__ ew) {
  int v = blockIdx.x >> 2;
  int h = ((blockIdx.x & 3) << 8) + threadIdx.x;
  const float* er = emb + v * EE;
  float acc = bh[h];
#pragma unroll 4
  for (int e = 0; e < EE; ++e) acc += er[e] * We[e * HH + h];
  ew[v * HH + h] = acc;
}

// Pack W_h (f32 [K=1024][N=1024]) into f16 MFMA B-fragment image:
// per slice j: [nt 0..3][kt 0..31][lane 0..63] -> 16B (8 f16, k contiguous)
// B frag (16x16x32): n = lane&15, k = kt*32 + (lane>>4)*8 + e
__global__ void k_pack_wh(const float* __restrict__ Wh, ulonglong2* __restrict__ img) {
  int gid = blockIdx.x * 256 + threadIdx.x;   // 512 blocks -> 131072 threads
  int lane = gid & 63;
  int fid  = gid >> 6;                        // ((j*4+nt)*32+kt), 0..2047
  int kt = fid & 31;
  int nt = (fid >> 5) & 3;
  int j  = fid >> 7;
  int n  = j * HCC + nt * 16 + (lane & 15);
  int kb = kt * 32 + (lane >> 4) * 8;
  U16x8 u;
#pragma unroll
  for (int e = 0; e < 8; ++e) u.h[e] = (_Float16)Wh[(kb + e) * HH + n];
  img[fid * 64 + lane] = u.u2;
}

// Pack W_out (f32 [K=1024][V=256]) into f16 B-fragment image: [jv 0..15][kt 0..31][lane]
__global__ void k_pack_wout(const float* __restrict__ Wo, ulonglong2* __restrict__ img) {
  int gid = blockIdx.x * 256 + threadIdx.x;   // 128 blocks -> 32768 threads
  int lane = gid & 63;
  int fid  = gid >> 6;                        // jv*32+kt, 0..511
  int kt = fid & 31;
  int jv = fid >> 5;
  int n  = jv * 16 + (lane & 15);
  int kb = kt * 32 + (lane >> 4) * 8;
  U16x8 u;
#pragma unroll
  for (int e = 0; e < 8; ++e) u.h[e] = (_Float16)Wo[(kb + e) * VV + n];
  img[fid * 64 + lane] = u.u2;
}

// S[par=0] = split(hidden) into hi/lo planes; zero barrier counters
__global__ void k_init(const float* __restrict__ hidden, _Float16* __restrict__ S0,
                       unsigned int* __restrict__ cnt) {
  int gid = blockIdx.x * 256 + threadIdx.x;   // 512 blocks = 131072 threads
  float v = hidden[gid];
  _Float16 hi = (_Float16)v;
  _Float16 lo = (_Float16)((v - (float)hi) * LOSCL);
  S0[gid] = hi;                 // plane 0 (hi)
  S0[BB * HH + gid] = lo;       // plane 1 (lo, scaled x2048)
  if (gid < NCLUST) cnt[gid * 32] = 0u;
}

// ---------------- persistent scan kernel ----------------
// 128 blocks x 256 threads. block = (cluster c = bid&7 -> XCD, slice j = bid>>3).
// dyn LDS: [0,128KB) W_h frag image for slice j; then part[] f32 (PSTR-padded).
__launch_bounds__(256, 1)
__global__ void k_scan(const int* __restrict__ x, const float* __restrict__ bout,
                       float* __restrict__ logits, float* __restrict__ fhid,
                       char* __restrict__ ws) {
  extern __shared__ ulonglong2 lds2[];              // 8192 x 16B = W_h image
  float* part = (float*)&lds2[8192];                // [(wv*5+nt)*4+reg][PSTR] f32

  unsigned int* cnt = (unsigned int*)(ws + CNT_OFF);
  const float* ew = (const float*)(ws + EW_OFF);
  _Float16* S = (_Float16*)(ws + S_OFF);            // [par][plane][BB][HH]
  const ulonglong2* whimg = (const ulonglong2*)(ws + WHI_OFF);
  const ulonglong2* woimg = (const ulonglong2*)(ws + WOI_OFF);

  const int bid = blockIdx.x;
  const int c = bid & 7;          // cluster -> same XCD under round-robin dispatch
  const int j = bid >> 3;         // 0..15 column slice
  const int tid = threadIdx.x;
  const int wv = tid >> 6;        // wave 0..3 (K-split: ktiles wv*8 .. wv*8+7)
  const int lane = tid & 63;

  // stage this slice's W_h fragment image into LDS (one-time, ~128KB)
  {
    const ulonglong2* src = whimg + j * 8192;
#pragma unroll 4
    for (int idx = tid; idx < 8192; idx += 256) lds2[idx] = src[idx];
  }
  __syncthreads();

  const int cbase = c * BRR;
  unsigned int* mycnt = cnt + c * 32;

  // epilogue thread mapping (C/D frag: col=lane&15, row=(lane>>4)*4+reg)
  const int erow = tid >> 4;              // 0..15 (batch row within cluster)
  const int ecg  = tid & 15;              // col group
  const int ebrow = cbase + erow;
  const int elsrc = (erow >> 2) << 4;     // lane = ((row>>2)<<4) | col
  const int err_ = erow & 3;              // C/D reg index

  for (int i = 1; i <= LL + 1; ++i) {
    const int par = (i - 1) & 1;
    const _Float16* Ahi = S + (par * 2 + 0) * (BB * HH);
    const _Float16* Alo = S + (par * 2 + 1) * (BB * HH);

    // ---- load A fragments (h_{i-1} hi/lo) via agent-scope atomics ----
    // A frag (16x16x32): row = lane&15, k = (lane>>4)*8 + e
    U16x8 avh[8], avl[8];
    {
      const int brow = cbase + (lane & 15);
      const int foff = brow * HH + wv * 256 + (lane >> 4) * 8;   // f16 units, /4 = u64
      const u64* arh = (const u64*)(Ahi + foff);
      const u64* arl = (const u64*)(Alo + foff);
#pragma unroll
      for (int q = 0; q < 8; ++q) {
        avh[q].w[0] = __hip_atomic_load(arh + q * 8,     __ATOMIC_RELAXED, __HIP_MEMORY_SCOPE_AGENT);
        avh[q].w[1] = __hip_atomic_load(arh + q * 8 + 1, __ATOMIC_RELAXED, __HIP_MEMORY_SCOPE_AGENT);
        avl[q].w[0] = __hip_atomic_load(arl + q * 8,     __ATOMIC_RELAXED, __HIP_MEMORY_SCOPE_AGENT);
        avl[q].w[1] = __hip_atomic_load(arl + q * 8 + 1, __ATOMIC_RELAXED, __HIP_MEMORY_SCOPE_AGENT);
      }
    }

    f32x4 accH[5], accL[5];
#pragma unroll
    for (int nt = 0; nt < 5; ++nt) {
      accH[nt] = (f32x4){0.f, 0.f, 0.f, 0.f};
      accL[nt] = (f32x4){0.f, 0.f, 0.f, 0.f};
    }

    // ---- recurrence MFMAs: (h_hi + h_lo/2048) @ W_h[:, slice j] ----
    if (i <= LL) {
#pragma unroll
      for (int nt = 0; nt < 4; ++nt) {
        const ulonglong2* bsrc = lds2 + (nt * 32 + wv * 8) * 64 + lane;
#pragma unroll
        for (int q = 0; q < 8; ++q) {
          U16x8 b; b.u2 = bsrc[q * 64];
          accH[nt] = __builtin_amdgcn_mfma_f32_16x16x32_f16(avh[q].f, b.f, accH[nt], 0, 0, 0);
          accL[nt] = __builtin_amdgcn_mfma_f32_16x16x32_f16(avl[q].f, b.f, accL[nt], 0, 0, 0);
        }
      }
    }
    // ---- fused logits MFMAs: h_{i-1} @ W_out[:, 16-col slice j] (l = i-2) ----
    if (i >= 2) {
      const ulonglong2* bsrc = woimg + (j * 32 + wv * 8) * 64 + lane;
#pragma unroll
      for (int q = 0; q < 8; ++q) {
        U16x8 b; b.u2 = bsrc[q * 64];
        accH[4] = __builtin_amdgcn_mfma_f32_16x16x32_f16(avh[q].f, b.f, accH[4], 0, 0, 0);
        accL[4] = __builtin_amdgcn_mfma_f32_16x16x32_f16(avl[q].f, b.f, accL[4], 0, 0, 0);
      }
    }

    // ---- cross-wave K reduction via LDS (combine hi + lo/2048 first) ----
    __syncthreads();   // previous iteration's part[] reads complete (WAR)
#pragma unroll
    for (int nt = 0; nt < 5; ++nt) {
      float* p = part + ((wv * 5 + nt) * 4) * PSTR + lane;
      p[0]        = accH[nt].x + accL[nt].x * ILOSCL;
      p[PSTR]     = accH[nt].y + accL[nt].y * ILOSCL;
      p[2 * PSTR] = accH[nt].z + accL[nt].z * ILOSCL;
      p[3 * PSTR] = accH[nt].w + accL[nt].w * ILOSCL;
    }
    __syncthreads();

    // ---- epilogue ----
    if (i <= LL) {
      const int tok = x[ebrow * LL + (i - 1)];
      const float4 xw = *(const float4*)(ew + tok * HH + j * HCC + ecg * 4);
      const float xwv[4] = {xw.x, xw.y, xw.z, xw.w};
      float hv[4];
#pragma unroll
      for (int k = 0; k < 4; ++k) {
        const int ccol = ecg * 4 + k;
        const int nt = ccol >> 4, cc = ccol & 15;
        float sum = xwv[k];
#pragma unroll
        for (int w2 = 0; w2 < 4; ++w2) sum += part[((w2 * 5 + nt) * 4 + err_) * PSTR + elsrc + cc];
        hv[k] = tanhf(sum);
      }
      U16x8 hb, lb;
#pragma unroll
      for (int k = 0; k < 4; ++k) {
        hb.h[k] = (_Float16)hv[k];
        lb.h[k] = (_Float16)((hv[k] - (float)hb.h[k]) * LOSCL);
      }
      _Float16* Sw = S + ((i & 1) * 2) * (BB * HH) + ebrow * HH + j * HCC + ecg * 4;
      __hip_atomic_store((u64*)Sw, hb.w[0], __ATOMIC_RELAXED, __HIP_MEMORY_SCOPE_AGENT);
      __hip_atomic_store((u64*)(Sw + BB * HH), lb.w[0], __ATOMIC_RELAXED, __HIP_MEMORY_SCOPE_AGENT);
      if (i == LL) {
        float* fh = fhid + ebrow * HH + j * HCC + ecg * 4;
#pragma unroll
        for (int k = 0; k < 4; ++k) fh[k] = hv[k];   // f32 final hidden
      }
    }
    if (i >= 2) {
      float sum = bout[j * 16 + ecg];
#pragma unroll
      for (int w2 = 0; w2 < 4; ++w2) sum += part[((w2 * 5 + 4) * 4 + err_) * PSTR + elsrc + ecg];
      logits[(size_t)(ebrow * LL + (i - 2)) * VV + j * 16 + ecg] = sum;
    }

    // ---- cluster barrier (16 blocks): publish S[i], wait for peers ----
    if (i <= LL) {
      __syncthreads();   // drains vmcnt -> all agent-scope S stores complete
      if (tid == 0) {
        __hip_atomic_fetch_add(mycnt, 1u, __ATOMIC_RELEASE, __HIP_MEMORY_SCOPE_AGENT);
        const unsigned int target = (unsigned int)(JJ * i);
        while (__hip_atomic_load(mycnt, __ATOMIC_ACQUIRE, __HIP_MEMORY_SCOPE_AGENT) < target)
          __builtin_amdgcn_s_sleep(2);
      }
      __syncthreads();
    }
  }
}

// ---------------- host launcher ----------------
extern "C" void kernel_launch(void* const* d_in, const int* in_sizes, int n_in,
                              void* d_out, int out_size, void* d_ws, size_t ws_size,
                              hipStream_t stream) {
  const int*   x      = (const int*)d_in[0];
  const float* hidden = (const float*)d_in[1];
  const float* emb    = (const float*)d_in[2];
  const float* We     = (const float*)d_in[3];
  const float* Wh     = (const float*)d_in[4];
  const float* bh     = (const float*)d_in[5];
  const float* Wout   = (const float*)d_in[6];
  const float* bout   = (const float*)d_in[7];

  float* logits = (float*)d_out;
  float* fhid   = logits + (size_t)BB * LL * VV;
  char* ws = (char*)d_ws;

  k_embedw   <<<1024, 256, 0, stream>>>(emb, We, bh, (float*)(ws + EW_OFF));
  k_pack_wh  <<< 512, 256, 0, stream>>>(Wh, (ulonglong2*)(ws + WHI_OFF));
  k_pack_wout<<< 128, 256, 0, stream>>>(Wout, (ulonglong2*)(ws + WOI_OFF));
  k_init     <<< 512, 256, 0, stream>>>(hidden, (_Float16*)(ws + S_OFF),
                                        (unsigned int*)(ws + CNT_OFF));

  // dyn LDS: W_h image 131072 B + part[] (79*PSTR+64 words, padded) = 21760 B
  const int dyn_lds = 8192 * 16 + 21760;   // 152832 <= 160KB
  hipFuncSetAttribute((const void*)k_scan, hipFuncAttributeMaxDynamicSharedMemorySize, dyn_lds);
  k_scan<<<128, 256, dyn_lds, stream>>>(x, bout, logits, fhid, ws);
}